// Round 5
// baseline (528.253 us; speedup 1.0000x reference)
//
#include <hip/hip_runtime.h>
#include <hip/hip_bf16.h>

#define NN 512
#define MM (NN*NN)   // 262144 rows

typedef __attribute__((ext_vector_type(8))) unsigned short u16x8;
typedef __attribute__((ext_vector_type(4))) unsigned short u16x4;
typedef __attribute__((ext_vector_type(8))) __bf16 bf16x8;
typedef __attribute__((ext_vector_type(4))) float f32x4;

static __device__ __forceinline__ unsigned short f2bfi(float f) {
  return __builtin_bit_cast(unsigned short, __float2bfloat16(f));
}
static __device__ __forceinline__ float bf2f(unsigned short h) {
  return __uint_as_float(((unsigned int)h) << 16);
}
static __device__ __forceinline__ bf16x8 ldfrag(const unsigned short* p) {
  u16x8 v = *(const u16x8*)p;
  return __builtin_bit_cast(bf16x8, v);
}
static __device__ __forceinline__ float sigm(float x) {
  return 1.0f / (1.0f + __expf(-x));
}

// ---------------- prep: WT_lu[n][k] for K3; WF fragment-ordered weights for K1 ---------
// WF[gm][nt][ks][lane][j]: col = nt*16+(lane&15), k = ks*32+(lane>>4)*8+j, gm in {ga,la,gb,lb,g}
__global__ void prep_weights(const float* __restrict__ ga_w, const float* __restrict__ la_w,
                             const float* __restrict__ gb_w, const float* __restrict__ lb_w,
                             const float* __restrict__ g_w,  const float* __restrict__ lu_w,
                             unsigned short* __restrict__ WT_lu, unsigned short* __restrict__ WF) {
  int idx = blockIdx.x * 256 + threadIdx.x;   // 384*256 = 98304 = 16384 + 81920
  if (idx < 16384) {
    int n = idx >> 7, k = idx & 127;
    WT_lu[idx] = f2bfi(lu_w[k * 128 + n]);
  } else {
    int id2 = idx - 16384;
    int j = id2 & 7, lane = (id2 >> 3) & 63, ks = (id2 >> 9) & 3, nt = (id2 >> 11) & 7, gm = id2 >> 14;
    int col = nt * 16 + (lane & 15);
    int k = ks * 32 + (lane >> 4) * 8 + j;
    const float* tabs[5] = {ga_w, la_w, gb_w, lb_w, g_w};
    WF[id2] = f2bfi(tabs[gm][k * 128 + col]);
  }
}

// ---------------- K0: LayerNorm -> z_g in MFMA-fragment order --------------------------
// z_g[tile][m(8)][ks(4)][lane(64)][j(8)] bf16; grid M/128 x 512 threads
__global__ __launch_bounds__(512) void k0_ln(
    const float* __restrict__ pair, const float* __restrict__ lng, const float* __restrict__ lnb,
    unsigned short* __restrict__ z_g) {
  const int t = threadIdx.x;
  const size_t m0 = (size_t)blockIdx.x * 128;
  const int row = t >> 2, q = t & 3;
  const float* pr = pair + (m0 + row) * 128 + q * 32;
  float vals[32];
  float s = 0.f, ss = 0.f;
#pragma unroll
  for (int it = 0; it < 8; ++it) {
    f32x4 v = __builtin_nontemporal_load((const f32x4*)(pr + it * 4));
#pragma unroll
    for (int j = 0; j < 4; ++j) { float x = v[j]; vals[it * 4 + j] = x; s += x; ss += x * x; }
  }
  s += __shfl_xor(s, 1);  s += __shfl_xor(s, 2);
  ss += __shfl_xor(ss, 1); ss += __shfl_xor(ss, 2);
  const float mean = s * (1.f / 128.f);
  const float var  = ss * (1.f / 128.f) - mean * mean;
  const float rstd = rsqrtf(var + 1e-5f);
  // dest: el = tile*16384 + (row>>4)*2048 + q*512 + ((row&15)+16*o)*8 + j
  unsigned short* zt = z_g + (size_t)blockIdx.x * 16384 + (row >> 4) * 2048 + q * 512 + (row & 15) * 8;
#pragma unroll
  for (int o = 0; o < 4; ++o) {
    u16x8 pk;
#pragma unroll
    for (int j = 0; j < 8; ++j) {
      int c = q * 32 + o * 8 + j;
      pk[j] = f2bfi((vals[o * 8 + j] - mean) * rstd * lng[c] + lnb[c]);
    }
    __builtin_nontemporal_store(pk, (u16x8*)(zt + o * 128));
  }
}

// ---------------- K1: 5 projections from fragment-ordered z and WF ---------------------
// grid M/128, 512 threads (8 waves); wave = 16 rows x 128 cols; af in regs for all 5 GEMMs.
__global__ __launch_bounds__(512, 4) void k1_proj5(
    const unsigned short* __restrict__ z_g, const unsigned short* __restrict__ WF,
    const float* __restrict__ ga_b, const float* __restrict__ la_b,
    const float* __restrict__ gb_b, const float* __restrict__ lb_b,
    const float* __restrict__ g_b,
    unsigned short* __restrict__ a_t, unsigned short* __restrict__ b_t,
    unsigned short* __restrict__ g_buf) {
  __shared__ __align__(16) unsigned short sW[2][16384];   // 65536 B total
  const int t = threadIdx.x;
  const size_t m0 = (size_t)blockIdx.x * 128;
  const int wave = t >> 6, lane = t & 63, lrow = lane & 15, qk = lane >> 4;

  // A-fragments (wave's 16 z rows, all K) straight from global, NT
  const u16x8* zp = (const u16x8*)z_g + ((size_t)blockIdx.x * 8 + wave) * 256 + lane;
  bf16x8 af[4];
#pragma unroll
  for (int ks = 0; ks < 4; ++ks)
    af[ks] = __builtin_bit_cast(bf16x8, __builtin_nontemporal_load(zp + ks * 64));

  u16x8 r0[4], r1[4];
  auto stage_ld = [&](u16x8* r, int gm) {
    const u16x8* src = (const u16x8*)WF + gm * 2048 + t;
#pragma unroll
    for (int rr = 0; rr < 4; ++rr) r[rr] = src[rr * 512];
  };
  auto stage_st = [&](int buf, const u16x8* r) {
    u16x8* d = (u16x8*)sW[buf] + t;
#pragma unroll
    for (int rr = 0; rr < 4; ++rr) d[rr * 512] = r[rr];
  };

  f32x4 accg[8], accl[8];
  auto run_gemm = [&](int buf, f32x4* acc) {
#pragma unroll
    for (int nt = 0; nt < 8; ++nt)
#pragma unroll
      for (int r = 0; r < 4; ++r) acc[nt][r] = 0.f;
#pragma unroll
    for (int ks = 0; ks < 4; ++ks)
#pragma unroll
      for (int nt = 0; nt < 8; ++nt) {
        bf16x8 bv = ldfrag(sW[buf] + ((nt * 4 + ks) * 64 + lane) * 8);
        acc[nt] = __builtin_amdgcn_mfma_f32_16x16x32_bf16(af[ks], bv, acc[nt], 0, 0, 0);
      }
  };
  // epilogue a/b: gate, stage transposed+swizzled [col][row] in sW[buf] (32 KB)
  auto epi_ab = [&](int buf, const float* gbias, const float* lbias) {
    char* st = (char*)sW[buf];
    const int rbyte = (wave * 16 + qk * 4) * 2;
#pragma unroll
    for (int nt = 0; nt < 8; ++nt) {
      int col = nt * 16 + lrow;
      float bg = gbias[col], bl = lbias[col];
      u16x4 pk;
#pragma unroll
      for (int r = 0; r < 4; ++r)
        pk[r] = f2bfi(sigm(accg[nt][r] + bg) * (accl[nt][r] + bl));
      *(u16x4*)(st + col * 256 + (rbyte ^ ((col & 7) << 5))) = pk;
    }
  };
  auto wout = [&](unsigned short* dst, int buf) {
    const char* st = (const char*)sW[buf];
#pragma unroll
    for (int it = 0; it < 4; ++it) {
      int idx = it * 512 + t;
      int col = idx >> 4, i = idx & 15;
      u16x8 v = *(const u16x8*)(st + col * 256 + ((i * 16) ^ ((col & 7) << 5)));
      __builtin_nontemporal_store(v, (u16x8*)(dst + (size_t)col * MM + m0 + i * 8));
    }
  };

  stage_ld(r0, 0);                     // ga
  stage_ld(r1, 1);                     // la
  stage_st(0, r0);
  stage_st(1, r1);
  stage_ld(r0, 2);                     // gb (issue early)
  __syncthreads();                     // b1
  run_gemm(0, accg);                   // ga
  run_gemm(1, accl);                   // la
  stage_ld(r1, 3);                     // lb
  __syncthreads();                     // b2: W0,W1 free
  stage_st(1, r0);                     // gb -> W1
  epi_ab(0, ga_b, la_b);               // a -> W0 (swz)
  stage_ld(r0, 4);                     // g
  __syncthreads();                     // b3
  wout(a_t, 0);
  run_gemm(1, accg);                   // gb
  __syncthreads();                     // b4: W0,W1 free
  stage_st(0, r1);                     // lb -> W0
  __syncthreads();                     // b5
  run_gemm(0, accl);                   // lb
  __syncthreads();                     // b6: W0 free
  epi_ab(0, gb_b, lb_b);               // b -> W0 (swz)
  stage_st(1, r0);                     // g -> W1
  __syncthreads();                     // b7
  wout(b_t, 0);
  run_gemm(1, accg);                   // g
  __syncthreads();                     // b8
  // g epilogue: row-major staging [128][136] flat across sW, then coalesced NT copy-out
  {
    unsigned short* gs = &sW[0][0];
#pragma unroll
    for (int nt = 0; nt < 8; ++nt) {
      int col = nt * 16 + lrow;
      float bg = g_b[col];
#pragma unroll
      for (int r = 0; r < 4; ++r)
        gs[(wave * 16 + qk * 4 + r) * 136 + col] = f2bfi(sigm(accg[nt][r] + bg));
    }
    __syncthreads();                   // b9
#pragma unroll
    for (int it = 0; it < 4; ++it) {
      int idx = it * 512 + t;
      int mr = idx >> 4, off = (idx & 15) * 8;
      u16x8 v = *(const u16x8*)(gs + mr * 136 + off);
      __builtin_nontemporal_store(v, (u16x8*)(g_buf + (m0 + mr) * 128 + off));
    }
  }
}

// ---------------- K2: channel-batched NT GEMM, 256x256 tiles ---------------------------
// grid 512 = 128 ch x 4 tiles (2x2 of 256), XCD-chunked; BK=32 double-buffered.
__global__ __launch_bounds__(512, 4) void k2_einsum(
    const unsigned short* __restrict__ a_t, const unsigned short* __restrict__ b_t,
    unsigned short* __restrict__ up_t) {
  __shared__ __align__(16) unsigned short sA[2][256 * 34];
  __shared__ __align__(16) unsigned short sB[2][256 * 34];   // 69632 B total
  const int t = threadIdx.x;
  const int wid = (blockIdx.x & 7) * 64 + (blockIdx.x >> 3);   // 64 consecutive wids per XCD
  const int c = wid >> 2;
  const int i0 = ((wid >> 1) & 1) * 256, j0 = (wid & 1) * 256;
  const unsigned short* Ag = a_t + (size_t)c * MM + (size_t)i0 * 512;
  const unsigned short* Bg = b_t + (size_t)c * MM + (size_t)j0 * 512;
  const int wave = t >> 6, lane = t & 63, wr = wave >> 2, wc = wave & 3;
  const int lrow = lane & 15, qk = lane >> 4;
  f32x4 acc[8][4];
#pragma unroll
  for (int i = 0; i < 8; ++i)
#pragma unroll
    for (int j = 0; j < 4; ++j)
#pragma unroll
      for (int r = 0; r < 4; ++r) acc[i][j][r] = 0.f;

  u16x8 ra[2], rb[2];
  auto tile_ld = [&](int k0) {
#pragma unroll
    for (int h = 0; h < 2; ++h) {
      int idx = h * 512 + t;
      int row = idx >> 2, qq = idx & 3;
      ra[h] = *(const u16x8*)(Ag + (size_t)row * 512 + k0 + qq * 8);
      rb[h] = *(const u16x8*)(Bg + (size_t)row * 512 + k0 + qq * 8);
    }
  };
  auto tile_st = [&](int buf) {
#pragma unroll
    for (int h = 0; h < 2; ++h) {
      int idx = h * 512 + t;
      int row = idx >> 2, qq = idx & 3;
      *(u16x8*)(sA[buf] + row * 34 + qq * 8) = ra[h];
      *(u16x8*)(sB[buf] + row * 34 + qq * 8) = rb[h];
    }
  };

  tile_ld(0);
  tile_st(0);
  __syncthreads();
  int cur = 0;
  for (int ks = 0; ks < 16; ++ks) {
    if (ks < 15) tile_ld((ks + 1) * 32);
    bf16x8 afr[8], bv[4];
#pragma unroll
    for (int mt = 0; mt < 8; ++mt)
      afr[mt] = ldfrag(sA[cur] + (wr * 128 + mt * 16 + lrow) * 34 + qk * 8);
#pragma unroll
    for (int nt = 0; nt < 4; ++nt)
      bv[nt] = ldfrag(sB[cur] + (wc * 64 + nt * 16 + lrow) * 34 + qk * 8);
#pragma unroll
    for (int mt = 0; mt < 8; ++mt)
#pragma unroll
      for (int nt = 0; nt < 4; ++nt)
        acc[mt][nt] = __builtin_amdgcn_mfma_f32_16x16x32_bf16(afr[mt], bv[nt], acc[mt][nt], 0, 0, 0);
    if (ks < 15) tile_st(cur ^ 1);
    __syncthreads();
    cur ^= 1;
  }
  unsigned short* up = up_t + (size_t)c * MM;
#pragma unroll
  for (int mt = 0; mt < 8; ++mt)
#pragma unroll
    for (int nt = 0; nt < 4; ++nt) {
      int col = j0 + wc * 64 + nt * 16 + lrow;
#pragma unroll
      for (int r = 0; r < 4; ++r) {
        int row = i0 + wr * 128 + mt * 16 + qk * 4 + r;
        up[(size_t)row * 512 + col] = f2bfi(acc[mt][nt][r]);
      }
    }
}

// ---------------- K3: LN(update) @ lu_w + lu_b, * g -> out -----------------------------
// grid M/64
__global__ __launch_bounds__(256) void k3_final(
    const unsigned short* __restrict__ up_t, const unsigned short* __restrict__ g_buf,
    const unsigned short* __restrict__ WT_lu,
    const float* __restrict__ lnug, const float* __restrict__ lnub,
    const float* __restrict__ lu_b, float* __restrict__ out) {
  __shared__ __align__(16) unsigned short sU[64 * 138];
  __shared__ __align__(16) unsigned short sA[64 * 136];
  __shared__ __align__(16) unsigned short sB[128 * 136];
  const int t = threadIdx.x;
  const size_t m0 = (size_t)blockIdx.x * 64;
#pragma unroll
  for (int it = 0; it < 4; ++it) {
    int idx = it * 256 + t;
    int c = idx >> 3, m8 = (idx & 7) * 8;
    u16x8 v = __builtin_nontemporal_load((const u16x8*)(up_t + (size_t)c * MM + m0 + m8));
#pragma unroll
    for (int j = 0; j < 8; ++j) sU[(m8 + j) * 138 + c] = v[j];
  }
#pragma unroll
  for (int it = 0; it < 8; ++it) {
    int idx = it * 256 + t;
    int n = idx >> 4, off = (idx & 15) * 8;
    *(u16x8*)(sB + n * 136 + off) = *(const u16x8*)(WT_lu + (size_t)n * 128 + off);
  }
  __syncthreads();
  {
    const int row = t >> 2, q = t & 3;
    float vals[32]; float s = 0.f, ss = 0.f;
#pragma unroll
    for (int jj = 0; jj < 32; ++jj) {
      int cc = q + jj * 4;
      float x = bf2f(sU[row * 138 + cc]);
      vals[jj] = x; s += x; ss += x * x;
    }
    s += __shfl_xor(s, 1);  s += __shfl_xor(s, 2);
    ss += __shfl_xor(ss, 1); ss += __shfl_xor(ss, 2);
    float mean = s * (1.f / 128.f);
    float var  = ss * (1.f / 128.f) - mean * mean;
    float rstd = rsqrtf(var + 1e-5f);
#pragma unroll
    for (int jj = 0; jj < 32; ++jj) {
      int cc = q + jj * 4;
      float zn = (vals[jj] - mean) * rstd * lnug[cc] + lnub[cc];
      sA[row * 136 + cc] = f2bfi(zn);
    }
  }
  __syncthreads();
  const int wave = t >> 6, lane = t & 63, lrow = lane & 15, qk = lane >> 4;
  f32x4 acc[8];
#pragma unroll
  for (int i = 0; i < 8; ++i)
#pragma unroll
    for (int r = 0; r < 4; ++r) acc[i][r] = 0.f;
#pragma unroll
  for (int ks = 0; ks < 4; ++ks) {
    int k0 = ks * 32;
    bf16x8 af = ldfrag(sA + (wave * 16 + lrow) * 136 + k0 + 8 * qk);
#pragma unroll
    for (int nt = 0; nt < 8; ++nt) {
      bf16x8 bv = ldfrag(sB + (nt * 16 + lrow) * 136 + k0 + 8 * qk);
      acc[nt] = __builtin_amdgcn_mfma_f32_16x16x32_bf16(af, bv, acc[nt], 0, 0, 0);
    }
  }
#pragma unroll
  for (int nt = 0; nt < 8; ++nt) {
    int e = nt * 16 + lrow;
    float bb = lu_b[e];
#pragma unroll
    for (int r = 0; r < 4; ++r) {
      size_t m = m0 + wave * 16 + qk * 4 + r;
      float lin = acc[nt][r] + bb;
      float gv = bf2f(g_buf[m * 128 + e]);
      out[m * 128 + e] = gv * lin;
    }
  }
}

extern "C" void kernel_launch(void* const* d_in, const int* in_sizes, int n_in,
                              void* d_out, int out_size, void* d_ws, size_t ws_size,
                              hipStream_t stream) {
  const float* pair = (const float*)d_in[0];
  const float* lng  = (const float*)d_in[1];
  const float* lnb  = (const float*)d_in[2];
  const float* ga_w = (const float*)d_in[3];
  const float* ga_b = (const float*)d_in[4];
  const float* la_w = (const float*)d_in[5];
  const float* la_b = (const float*)d_in[6];
  const float* gb_w = (const float*)d_in[7];
  const float* gb_b = (const float*)d_in[8];
  const float* lb_w = (const float*)d_in[9];
  const float* lb_b = (const float*)d_in[10];
  const float* g_w  = (const float*)d_in[11];
  const float* g_b  = (const float*)d_in[12];
  const float* lnug = (const float*)d_in[13];
  const float* lnub = (const float*)d_in[14];
  const float* lu_w = (const float*)d_in[15];
  const float* lu_b = (const float*)d_in[16];
  float* out = (float*)d_out;

  char* ws = (char*)d_ws;
  unsigned short* WT_lu = (unsigned short*)(ws);                   // 32768 B
  unsigned short* WF    = (unsigned short*)(ws + 32768ull);        // 163840 B -> 196608
  unsigned short* zup   = (unsigned short*)(ws + 196608ull);       // z_g (K0/K1) ALIASES up_t (K2/K3)
  unsigned short* a_t   = (unsigned short*)(ws + 67305472ull);     // 128*M*2
  unsigned short* b_t   = (unsigned short*)(ws + 134414336ull);    // 128*M*2
  unsigned short* g_buf = (unsigned short*)(ws + 201523200ull);    // M*128*2 (end ~268.6 MB)

  hipLaunchKernelGGL(prep_weights, dim3(384), dim3(256), 0, stream,
                     ga_w, la_w, gb_w, lb_w, g_w, lu_w, WT_lu, WF);
  hipLaunchKernelGGL(k0_ln, dim3(2048), dim3(512), 0, stream, pair, lng, lnb, zup);
  hipLaunchKernelGGL(k1_proj5, dim3(2048), dim3(512), 0, stream,
                     zup, WF, ga_b, la_b, gb_b, lb_b, g_b, a_t, b_t, g_buf);
  hipLaunchKernelGGL(k2_einsum, dim3(512), dim3(512), 0, stream, a_t, b_t, zup);
  hipLaunchKernelGGL(k3_final, dim3(4096), dim3(256), 0, stream,
                     zup, g_buf, WT_lu, lnug, lnub, lu_b, out);
}

// Round 6
// 282.732 us; speedup vs baseline: 1.8684x; 1.8684x over previous
//
#include <hip/hip_runtime.h>
#include <hip/hip_bf16.h>

#define NN 512
#define MM (NN*NN)   // 262144 rows

typedef __attribute__((ext_vector_type(8))) unsigned short u16x8;
typedef __attribute__((ext_vector_type(4))) unsigned short u16x4;
typedef __attribute__((ext_vector_type(8))) __bf16 bf16x8;
typedef __attribute__((ext_vector_type(4))) float f32x4;

static __device__ __forceinline__ unsigned short f2bfi(float f) {
  return __builtin_bit_cast(unsigned short, __float2bfloat16(f));
}
static __device__ __forceinline__ float bf2f(unsigned short h) {
  return __uint_as_float(((unsigned int)h) << 16);
}
static __device__ __forceinline__ bf16x8 ldfrag(const unsigned short* p) {
  u16x8 v = *(const u16x8*)p;
  return __builtin_bit_cast(bf16x8, v);
}
static __device__ __forceinline__ float sigm(float x) {
  // v_exp + v_rcp instead of the ~8-op IEEE divide sequence
  return __builtin_amdgcn_rcpf(1.0f + __expf(-x));
}

// ---------------- prep: WT[n][k] (bf16), n: [ga|la|gb|lb|g|lu] x 128 cols, k = 128 ----
__global__ void prep_weights(const float* __restrict__ ga_w, const float* __restrict__ la_w,
                             const float* __restrict__ gb_w, const float* __restrict__ lb_w,
                             const float* __restrict__ g_w,  const float* __restrict__ lu_w,
                             unsigned short* __restrict__ WT) {
  int idx = blockIdx.x * 256 + threadIdx.x;
  if (idx >= 768 * 128) return;
  int n = idx >> 7;     // output row (col of original weight)
  int k = idx & 127;    // reduction index
  int grp = n >> 7, cn = n & 127;
  const float* tabs[6] = {ga_w, la_w, gb_w, lb_w, g_w, lu_w};
  WT[idx] = f2bfi(tabs[grp][k * 128 + cn]);
}

// ---------------- K1: fused LN + 5 projections, double-buffered 2-phase schedule -------
// grid.x = M/128, block = 512 (8 waves); wave owns 16 rows x 128 cols per GEMM.
__global__ __launch_bounds__(512, 4) void k1_proj(
    const float* __restrict__ pair, const float* __restrict__ lng, const float* __restrict__ lnb,
    const unsigned short* __restrict__ WT,
    const float* __restrict__ ga_b, const float* __restrict__ la_b,
    const float* __restrict__ gb_b, const float* __restrict__ lb_b,
    const float* __restrict__ g_b,
    unsigned short* __restrict__ a_t, unsigned short* __restrict__ b_t,
    unsigned short* __restrict__ g_buf) {
  __shared__ __align__(16) unsigned short W0[128 * 136];
  __shared__ __align__(16) unsigned short W1[128 * 136];
  const int t = threadIdx.x;
  const size_t m0 = (size_t)blockIdx.x * 128;
  const int wave = t >> 6, lane = t & 63, lrow = lane & 15, qk = lane >> 4;
  const int rbase = t >> 4, off_ = (t & 15) * 8;

  u16x8 rga[4], rla[4], rgb[4], rlb[4], rg[4];
  auto stage_ld = [&](u16x8* r, int base) {
#pragma unroll
    for (int it = 0; it < 4; ++it)
      r[it] = *(const u16x8*)(WT + (size_t)(base + it * 32 + rbase) * 128 + off_);
  };
  auto stage_st = [&](unsigned short* buf, const u16x8* r) {
#pragma unroll
    for (int it = 0; it < 4; ++it)
      *(u16x8*)(buf + (it * 32 + rbase) * 136 + off_) = r[it];
  };

  // issue first two weight loads before LN so HBM/L2 latency hides under LN math
  stage_ld(rga, 0);
  stage_ld(rla, 128);

  // ---- LN: 128 rows -> W0 (bf16) ----
  {
    const int row = t >> 2, q = t & 3;
    const float* pr = pair + (m0 + row) * 128 + q * 32;
    float vals[32];
    float s = 0.f, ss = 0.f;
#pragma unroll
    for (int it = 0; it < 8; ++it) {
      f32x4 v = *(const f32x4*)(pr + it * 4);
#pragma unroll
      for (int j = 0; j < 4; ++j) { float x = v[j]; vals[it * 4 + j] = x; s += x; ss += x * x; }
    }
    s += __shfl_xor(s, 1);  s += __shfl_xor(s, 2);
    ss += __shfl_xor(ss, 1); ss += __shfl_xor(ss, 2);
    const float mean = s * (1.f / 128.f);
    const float var  = ss * (1.f / 128.f) - mean * mean;
    const float rstd = rsqrtf(var + 1e-5f);
#pragma unroll
    for (int i = 0; i < 4; ++i) {
      u16x8 pk;
#pragma unroll
      for (int j = 0; j < 8; ++j) {
        int c = q * 32 + i * 8 + j;
        pk[j] = f2bfi((vals[i * 8 + j] - mean) * rstd * lng[c] + lnb[c]);
      }
      *(u16x8*)(W0 + row * 136 + q * 32 + i * 8) = pk;
    }
  }
  __syncthreads();                                            // b0: LN in W0

  bf16x8 af[4];
  f32x4 accg[8], accl[8];
  auto run_gemm = [&](const unsigned short* buf, f32x4* acc) {
#pragma unroll
    for (int nt = 0; nt < 8; ++nt)
#pragma unroll
      for (int r = 0; r < 4; ++r) acc[nt][r] = 0.f;
#pragma unroll
    for (int ks = 0; ks < 4; ++ks)
#pragma unroll
      for (int nt = 0; nt < 8; ++nt) {
        bf16x8 bv = ldfrag(buf + (nt * 16 + lrow) * 136 + ks * 32 + 8 * qk);
        acc[nt] = __builtin_amdgcn_mfma_f32_16x16x32_bf16(af[ks], bv, acc[nt], 0, 0, 0);
      }
  };
  auto epi_ab = [&](unsigned short* buf, const float* gbias, const float* lbias) {
#pragma unroll
    for (int nt = 0; nt < 8; ++nt) {
      int col = nt * 16 + lrow;
      float bg = gbias[col], bl = lbias[col];
      u16x4 pk;
#pragma unroll
      for (int r = 0; r < 4; ++r)
        pk[r] = f2bfi(sigm(accg[nt][r] + bg) * (accl[nt][r] + bl));
      *(u16x4*)(buf + col * 136 + wave * 16 + qk * 4) = pk;
    }
  };
  auto wout = [&](unsigned short* dst, const unsigned short* buf) {
#pragma unroll
    for (int it = 0; it < 4; ++it) {
      int idx = it * 512 + t;
      int col = idx >> 4, i = idx & 15;
      *(u16x8*)(dst + (size_t)col * MM + m0 + i * 8) = *(const u16x8*)(buf + col * 136 + i * 8);
    }
  };

  // phase1: A-fragments from W0; stage ga -> W1; issue gb loads
#pragma unroll
  for (int ks = 0; ks < 4; ++ks)
    af[ks] = ldfrag(W0 + (wave * 16 + lrow) * 136 + ks * 32 + 8 * qk);
  stage_st(W1, rga);
  stage_ld(rgb, 256);
  __syncthreads();                                            // b1
  // phase2: GEMM ga(W1); stage la -> W0; issue lb loads
  run_gemm(W1, accg);
  stage_st(W0, rla);
  stage_ld(rlb, 384);
  __syncthreads();                                            // b2
  // phase3: GEMM la(W0); stage gb -> W1; issue g loads
  run_gemm(W0, accl);
  stage_st(W1, rgb);
  stage_ld(rg, 512);
  __syncthreads();                                            // b3
  // phase4: epilogue a -> W0 (transposed [col][row])
  epi_ab(W0, ga_b, la_b);
  __syncthreads();                                            // b4
  // phase5: write a_t from W0; GEMM gb(W1)
  wout(a_t, W0);
  run_gemm(W1, accg);
  __syncthreads();                                            // b5
  // phase6: stage lb -> W0, g -> W1
  stage_st(W0, rlb);
  stage_st(W1, rg);
  __syncthreads();                                            // b6
  // phase7: GEMM lb(W0)
  run_gemm(W0, accl);
  __syncthreads();                                            // b7
  // phase8: epilogue b -> W0; GEMM g(W1)
  epi_ab(W0, gb_b, lb_b);
  run_gemm(W1, accg);
  __syncthreads();                                            // b8
  // phase9: write b_t from W0; stage g row-major into W1 (free after b8)
  wout(b_t, W0);
#pragma unroll
  for (int nt = 0; nt < 8; ++nt) {
    int col = nt * 16 + lrow;
    float bg = g_b[col];
#pragma unroll
    for (int r = 0; r < 4; ++r)
      W1[(wave * 16 + qk * 4 + r) * 136 + col] = f2bfi(sigm(accg[nt][r] + bg));
  }
  __syncthreads();                                            // b9
  // phase10: coalesced g copy-out
#pragma unroll
  for (int it = 0; it < 4; ++it) {
    int idx = it * 512 + t;
    int mr = idx >> 4, off = (idx & 15) * 8;
    *(u16x8*)(g_buf + (m0 + mr) * 128 + off) = *(const u16x8*)(W1 + mr * 136 + off);
  }
}

// ---------------- K2: channel-batched NT GEMM update_t[c] = A_c * B_c^T ----------------
// 1-D grid 2048 = 128 channels x 16 tiles, XCD-chunk swizzled; double-buffered k-loop.
__global__ __launch_bounds__(256) void k2_einsum(
    const unsigned short* __restrict__ a_t, const unsigned short* __restrict__ b_t,
    unsigned short* __restrict__ up_t) {
  __shared__ __align__(16) unsigned short sA[2][128 * 40];
  __shared__ __align__(16) unsigned short sB[2][128 * 40];
  const int t = threadIdx.x;
  const int wid = (blockIdx.x & 7) * 256 + (blockIdx.x >> 3);
  const int c = wid >> 4;
  const int i0 = ((wid >> 2) & 3) * 128, j0 = (wid & 3) * 128;
  const unsigned short* Ag = a_t + (size_t)c * MM + (size_t)i0 * 512;
  const unsigned short* Bg = b_t + (size_t)c * MM + (size_t)j0 * 512;
  const int wave = t >> 6, lane = t & 63, wr = wave >> 1, wc = wave & 1;
  const int lrow = lane & 15, qk = lane >> 4;
  const int srow = t >> 2, sq = t & 3;
  f32x4 acc[4][4];
#pragma unroll
  for (int i = 0; i < 4; ++i)
#pragma unroll
    for (int j = 0; j < 4; ++j)
#pragma unroll
      for (int r = 0; r < 4; ++r) acc[i][j][r] = 0.f;

  u16x8 ra[2], rb[2];
  auto tile_ld = [&](int k0) {
#pragma unroll
    for (int h = 0; h < 2; ++h) {
      int row = h * 64 + srow;
      ra[h] = *(const u16x8*)(Ag + (size_t)row * 512 + k0 + sq * 8);
      rb[h] = *(const u16x8*)(Bg + (size_t)row * 512 + k0 + sq * 8);
    }
  };
  auto tile_st = [&](int buf) {
#pragma unroll
    for (int h = 0; h < 2; ++h) {
      int row = h * 64 + srow;
      *(u16x8*)(sA[buf] + row * 40 + sq * 8) = ra[h];
      *(u16x8*)(sB[buf] + row * 40 + sq * 8) = rb[h];
    }
  };

  tile_ld(0);
  tile_st(0);
  __syncthreads();
  int cur = 0;
  for (int ks = 0; ks < 16; ++ks) {
    if (ks < 15) tile_ld((ks + 1) * 32);
    bf16x8 afr[4], bv[4];
#pragma unroll
    for (int mt = 0; mt < 4; ++mt)
      afr[mt] = ldfrag(sA[cur] + (wr * 64 + mt * 16 + lrow) * 40 + 8 * qk);
#pragma unroll
    for (int nt = 0; nt < 4; ++nt)
      bv[nt] = ldfrag(sB[cur] + (wc * 64 + nt * 16 + lrow) * 40 + 8 * qk);
#pragma unroll
    for (int mt = 0; mt < 4; ++mt)
#pragma unroll
      for (int nt = 0; nt < 4; ++nt)
        acc[mt][nt] = __builtin_amdgcn_mfma_f32_16x16x32_bf16(afr[mt], bv[nt], acc[mt][nt], 0, 0, 0);
    if (ks < 15) tile_st(cur ^ 1);
    __syncthreads();
    cur ^= 1;
  }
  unsigned short* up = up_t + (size_t)c * MM;
#pragma unroll
  for (int mt = 0; mt < 4; ++mt)
#pragma unroll
    for (int nt = 0; nt < 4; ++nt) {
      int col = j0 + wc * 64 + nt * 16 + lrow;
#pragma unroll
      for (int r = 0; r < 4; ++r) {
        int row = i0 + wr * 64 + mt * 16 + qk * 4 + r;
        up[(size_t)row * 512 + col] = f2bfi(acc[mt][nt][r]);
      }
    }
}

// ---------------- K3: LN(update) @ lu_w + lu_b, * g -> out -----------------------------
// grid.x = M/64
__global__ __launch_bounds__(256) void k3_final(
    const unsigned short* __restrict__ up_t, const unsigned short* __restrict__ g_buf,
    const unsigned short* __restrict__ WT,
    const float* __restrict__ lnug, const float* __restrict__ lnub,
    const float* __restrict__ lu_b, float* __restrict__ out) {
  __shared__ __align__(16) unsigned short sU[64 * 138];
  __shared__ __align__(16) unsigned short sA[64 * 136];
  __shared__ __align__(16) unsigned short sB[128 * 136];
  const int t = threadIdx.x;
  const size_t m0 = (size_t)blockIdx.x * 64;
#pragma unroll
  for (int it = 0; it < 4; ++it) {
    int idx = it * 256 + t;
    int c = idx >> 3, m8 = (idx & 7) * 8;
    u16x8 v = *(const u16x8*)(up_t + (size_t)c * MM + m0 + m8);
#pragma unroll
    for (int j = 0; j < 8; ++j) sU[(m8 + j) * 138 + c] = v[j];
  }
#pragma unroll
  for (int it = 0; it < 8; ++it) {
    int idx = it * 256 + t;
    int n = idx >> 4, off = (idx & 15) * 8;
    *(u16x8*)(sB + n * 136 + off) = *(const u16x8*)(WT + (size_t)(640 + n) * 128 + off);
  }
  __syncthreads();
  {
    const int row = t >> 2, q = t & 3;
    float vals[32]; float s = 0.f, ss = 0.f;
#pragma unroll
    for (int jj = 0; jj < 32; ++jj) {
      int cc = q + jj * 4;
      float x = bf2f(sU[row * 138 + cc]);
      vals[jj] = x; s += x; ss += x * x;
    }
    s += __shfl_xor(s, 1);  s += __shfl_xor(s, 2);
    ss += __shfl_xor(ss, 1); ss += __shfl_xor(ss, 2);
    float mean = s * (1.f / 128.f);
    float var  = ss * (1.f / 128.f) - mean * mean;
    float rstd = rsqrtf(var + 1e-5f);
#pragma unroll
    for (int jj = 0; jj < 32; ++jj) {
      int cc = q + jj * 4;
      float zn = (vals[jj] - mean) * rstd * lnug[cc] + lnub[cc];
      sA[row * 136 + cc] = f2bfi(zn);
    }
  }
  __syncthreads();
  const int wave = t >> 6, lane = t & 63, lrow = lane & 15, qk = lane >> 4;
  f32x4 acc[8];
#pragma unroll
  for (int i = 0; i < 8; ++i)
#pragma unroll
    for (int r = 0; r < 4; ++r) acc[i][r] = 0.f;
#pragma unroll
  for (int ks = 0; ks < 4; ++ks) {
    int k0 = ks * 32;
    bf16x8 af = ldfrag(sA + (wave * 16 + lrow) * 136 + k0 + 8 * qk);
#pragma unroll
    for (int nt = 0; nt < 8; ++nt) {
      bf16x8 bv = ldfrag(sB + (nt * 16 + lrow) * 136 + k0 + 8 * qk);
      acc[nt] = __builtin_amdgcn_mfma_f32_16x16x32_bf16(af, bv, acc[nt], 0, 0, 0);
    }
  }
#pragma unroll
  for (int nt = 0; nt < 8; ++nt) {
    int e = nt * 16 + lrow;
    float bb = lu_b[e];
#pragma unroll
    for (int r = 0; r < 4; ++r) {
      size_t m = m0 + wave * 16 + qk * 4 + r;
      float lin = acc[nt][r] + bb;
      float gv = bf2f(g_buf[m * 128 + e]);
      out[m * 128 + e] = gv * lin;
    }
  }
}

extern "C" void kernel_launch(void* const* d_in, const int* in_sizes, int n_in,
                              void* d_out, int out_size, void* d_ws, size_t ws_size,
                              hipStream_t stream) {
  const float* pair = (const float*)d_in[0];
  const float* lng  = (const float*)d_in[1];
  const float* lnb  = (const float*)d_in[2];
  const float* ga_w = (const float*)d_in[3];
  const float* ga_b = (const float*)d_in[4];
  const float* la_w = (const float*)d_in[5];
  const float* la_b = (const float*)d_in[6];
  const float* gb_w = (const float*)d_in[7];
  const float* gb_b = (const float*)d_in[8];
  const float* lb_w = (const float*)d_in[9];
  const float* lb_b = (const float*)d_in[10];
  const float* g_w  = (const float*)d_in[11];
  const float* g_b  = (const float*)d_in[12];
  const float* lnug = (const float*)d_in[13];
  const float* lnub = (const float*)d_in[14];
  const float* lu_w = (const float*)d_in[15];
  const float* lu_b = (const float*)d_in[16];
  float* out = (float*)d_out;

  char* ws = (char*)d_ws;
  unsigned short* WT    = (unsigned short*)(ws);                  // 768*128*2   = 196608 B
  unsigned short* a_t   = (unsigned short*)(ws + 196608ull);      // 128*M*2     = 67108864 B
  unsigned short* b_t   = (unsigned short*)(ws + 67305472ull);    // 128*M*2
  unsigned short* g_buf = (unsigned short*)(ws + 134414336ull);   // M*128*2
  unsigned short* up_t  = (unsigned short*)(ws + 201523200ull);   // 128*M*2  (total ~268.6 MB)

  hipLaunchKernelGGL(prep_weights, dim3(384), dim3(256), 0, stream,
                     ga_w, la_w, gb_w, lb_w, g_w, lu_w, WT);
  hipLaunchKernelGGL(k1_proj, dim3(2048), dim3(512), 0, stream,
                     pair, lng, lnb, WT, ga_b, la_b, gb_b, lb_b, g_b, a_t, b_t, g_buf);
  hipLaunchKernelGGL(k2_einsum, dim3(2048), dim3(256), 0, stream, a_t, b_t, up_t);
  hipLaunchKernelGGL(k3_final, dim3(4096), dim3(256), 0, stream,
                     up_t, g_buf, WT, lnug, lnub, lu_b, out);
}